// Round 3
// baseline (698.159 us; speedup 1.0000x reference)
//
#include <hip/hip_runtime.h>

typedef unsigned short u16;
typedef __attribute__((ext_vector_type(8))) short short8;   // 8 bf16 = 4 VGPRs (MFMA A/B frag)
typedef __attribute__((ext_vector_type(4))) float f32x4;    // MFMA C/D frag

#define T_SEQ 4096
#define DMODEL 1024
#define NH 16
#define DKH 64
#define KPROJ 256

// ---------- bf16 helpers (bit-level, RNE) ----------
__device__ __forceinline__ u16 f2bf(float f) {
  union { float f; unsigned u; } v; v.f = f;
  unsigned r = v.u + 0x7FFFu + ((v.u >> 16) & 1u);
  return (u16)(r >> 16);
}
__device__ __forceinline__ float bf2f(u16 h) {
  union { unsigned u; float f; } v; v.u = ((unsigned)h) << 16; return v.f;
}

// ---------- dtype sniffer: fp32 data read as u16 has ~0.4% NaN/Inf bf16 patterns in the
// low halves (uniform mantissa bits); genuine finite bf16 data has exactly zero. ----------
__global__ void sniff_dtype(const u16* __restrict__ x, int* __restrict__ flag) {
  int c = 0;
  for (int i = threadIdx.x; i < 8192; i += 64)
    if ((x[2 * i] & 0x7F80) == 0x7F80) c++;   // exp==0xFF -> Inf/NaN bf16 pattern
#pragma unroll
  for (int m = 1; m < 64; m <<= 1) c += __shfl_xor(c, m);
  if (threadIdx.x == 0) *flag = (c > 0) ? 1 : 0;   // 1 = inputs are float32
}

// ---------- x -> bf16 (copy or downconvert), 8 elems/thread ----------
__global__ void convert_x(const void* __restrict__ xin, u16* __restrict__ xout,
                          const int* __restrict__ flag, int n) {
  const int i = (blockIdx.x * 256 + threadIdx.x) * 8;
  if (i >= n) return;
  if (*flag) {
    const float* f = (const float*)xin + i;
    union { u16 s[8]; short8 v; } o;
#pragma unroll
    for (int j = 0; j < 8; ++j) o.s[j] = f2bf(f[j]);
    *(short8*)(xout + i) = o.v;
  } else {
    *(short8*)(xout + i) = *(const short8*)((const u16*)xin + i);
  }
}

// ---------- tiled transpose + convert: out[c][r] = bf16(in[r][c]) ----------
__global__ void transpose_cvt(const void* __restrict__ in, u16* __restrict__ out,
                              int R, int C, const int* __restrict__ flag) {
  __shared__ u16 tile[32][33];
  const bool f32 = (*flag != 0);
  const int c0 = blockIdx.x * 32, r0 = blockIdx.y * 32;
  for (int i = threadIdx.y; i < 32; i += 8) {
    const size_t idx = (size_t)(r0 + i) * C + c0 + threadIdx.x;
    tile[i][threadIdx.x] = f32 ? f2bf(((const float*)in)[idx]) : ((const u16*)in)[idx];
  }
  __syncthreads();
  for (int i = threadIdx.y; i < 32; i += 8)
    out[(size_t)(c0 + i) * R + r0 + threadIdx.x] = tile[threadIdx.x][i];
}

// ---------- C = A(MxK) @ Bt(NxK)^T, 128x128 tile, BK=32, 4 waves, classic staging ----------
// MODE 0: C row-major bf16
// MODE 1: C row-major + bias[n]; output dtype (bf16/fp32) and bias dtype per *flag
// MODE 2: C per-head-transposed bf16: C[(b*NH+h)*DKH+d][t], m=b*T+t, n=h*DKH+d
template <int MODE>
__global__ void __launch_bounds__(256) gemm_bt(const u16* __restrict__ A, const u16* __restrict__ Bt,
                                               const void* __restrict__ bias, void* __restrict__ Cv,
                                               const int* __restrict__ flag, int M, int N, int K) {
  __shared__ __align__(16) u16 As[128 * 32];
  __shared__ __align__(16) u16 Bs[128 * 32];
  const int tid = threadIdx.x;
  const int wid = tid >> 6, lane = tid & 63;
  const int wm = wid >> 1, wn = wid & 1;
  const int quad = lane >> 4, l16 = lane & 15;
  const int m0 = blockIdx.y * 128, n0 = blockIdx.x * 128;
  const int srow = lane >> 2, scol = (lane & 3) * 8;   // wave stages 16 rows x 32 cols per chunk

  const u16* Ag = A + (size_t)(m0 + srow) * K + scol;
  const u16* Bg = Bt + (size_t)(n0 + srow) * K + scol;

  f32x4 acc[4][4] = {};

  for (int k0 = 0; k0 < K; k0 += 32) {
    short8 va[2], vb[2];
#pragma unroll
    for (int r = 0; r < 2; ++r) {
      const int rowb = r * 64 + wid * 16;
      va[r] = *(const short8*)(Ag + (size_t)rowb * K + k0);
      vb[r] = *(const short8*)(Bg + (size_t)rowb * K + k0);
    }
#pragma unroll
    for (int r = 0; r < 2; ++r) {
      const int row = r * 64 + wid * 16 + srow;
      *(short8*)(As + row * 32 + scol) = va[r];
      *(short8*)(Bs + row * 32 + scol) = vb[r];
    }
    __syncthreads();
    short8 a[4], b[4];
#pragma unroll
    for (int mi = 0; mi < 4; ++mi)
      a[mi] = *(const short8*)(As + (wm * 64 + mi * 16 + l16) * 32 + quad * 8);
#pragma unroll
    for (int ni = 0; ni < 4; ++ni)
      b[ni] = *(const short8*)(Bs + (wn * 64 + ni * 16 + l16) * 32 + quad * 8);
#pragma unroll
    for (int mi = 0; mi < 4; ++mi)
#pragma unroll
      for (int ni = 0; ni < 4; ++ni)
        acc[mi][ni] = __builtin_amdgcn_mfma_f32_16x16x32_bf16(a[mi], b[ni], acc[mi][ni], 0, 0, 0);
    __syncthreads();
  }

  const bool f32out = (MODE == 1) && (*flag != 0);
#pragma unroll
  for (int mi = 0; mi < 4; ++mi) {
#pragma unroll
    for (int ni = 0; ni < 4; ++ni) {
      const int mloc = wm * 64 + mi * 16 + quad * 4;      // row of acc reg 0
      const int n = n0 + wn * 64 + ni * 16 + l16;
      if (MODE == 2) {
        const int m = m0 + mloc;
        const int bb = m >> 12, t = m & (T_SEQ - 1);
        const int h = n >> 6, d = n & 63;
        union { u16 s[4]; uint2 v; } pk;
#pragma unroll
        for (int r = 0; r < 4; ++r) pk.s[r] = f2bf(acc[mi][ni][r]);
        *(uint2*)((u16*)Cv + (((size_t)(bb * NH + h)) * DKH + d) * T_SEQ + t) = pk.v;
      } else {
        float badd = 0.0f;
        if (MODE == 1)
          badd = f32out ? ((const float*)bias)[n] : bf2f(((const u16*)bias)[n]);
#pragma unroll
        for (int r = 0; r < 4; ++r) {
          const size_t oi = (size_t)(m0 + mloc + r) * N + n;
          if (f32out) ((float*)Cv)[oi] = acc[mi][ni][r] + badd;
          else        ((u16*)Cv)[oi]  = f2bf(acc[mi][ni][r] + badd);
        }
      }
    }
  }
}

// ---------- low-rank seq projection: per (b,h): Et(KP x T) @ Xt(DK x T)^T ----------
// grid (2, 64, 2): x = 128-row kp block, y = bh, z = which (0: K->Kp plain, 1: V->VpT transposed)
__global__ void __launch_bounds__(256) proj_bt(const u16* __restrict__ EkT, const u16* __restrict__ EvT,
                                               const u16* __restrict__ Kt, const u16* __restrict__ Vt,
                                               u16* __restrict__ Kp, u16* __restrict__ VpT) {
  const int which = blockIdx.z;
  const int bh = blockIdx.y;
  const int kpb = blockIdx.x;
  const u16* A = (which ? EvT : EkT) + (size_t)kpb * 128 * T_SEQ;
  const u16* Bt = (which ? Vt : Kt) + (size_t)bh * DKH * T_SEQ;
  __shared__ __align__(16) u16 As[128 * 32];
  __shared__ __align__(16) u16 Bs[64 * 32];
  const int tid = threadIdx.x, wid = tid >> 6, lane = tid & 63;
  const int wm = wid >> 1, wn = wid & 1, quad = lane >> 4, l16 = lane & 15;
  const int srow = lane >> 2, scol = (lane & 3) * 8;
  f32x4 acc[4][2] = {};

  for (int k0 = 0; k0 < T_SEQ; k0 += 32) {
    short8 va[2], vb;
#pragma unroll
    for (int r = 0; r < 2; ++r)
      va[r] = *(const short8*)(A + (size_t)(r * 64 + wid * 16 + srow) * T_SEQ + k0 + scol);
    vb = *(const short8*)(Bt + (size_t)(wid * 16 + srow) * T_SEQ + k0 + scol);
#pragma unroll
    for (int r = 0; r < 2; ++r)
      *(short8*)(As + (r * 64 + wid * 16 + srow) * 32 + scol) = va[r];
    *(short8*)(Bs + (wid * 16 + srow) * 32 + scol) = vb;
    __syncthreads();
    short8 a[4], b[2];
#pragma unroll
    for (int mi = 0; mi < 4; ++mi)
      a[mi] = *(const short8*)(As + (wm * 64 + mi * 16 + l16) * 32 + quad * 8);
#pragma unroll
    for (int ni = 0; ni < 2; ++ni)
      b[ni] = *(const short8*)(Bs + (wn * 32 + ni * 16 + l16) * 32 + quad * 8);
#pragma unroll
    for (int mi = 0; mi < 4; ++mi)
#pragma unroll
      for (int ni = 0; ni < 2; ++ni)
        acc[mi][ni] = __builtin_amdgcn_mfma_f32_16x16x32_bf16(a[mi], b[ni], acc[mi][ni], 0, 0, 0);
    __syncthreads();
  }

#pragma unroll
  for (int mi = 0; mi < 4; ++mi) {
#pragma unroll
    for (int ni = 0; ni < 2; ++ni) {
      const int kploc = kpb * 128 + wm * 64 + mi * 16 + quad * 4;
      const int d = wn * 32 + ni * 16 + l16;
      if (which == 0) {
#pragma unroll
        for (int r = 0; r < 4; ++r)
          Kp[((size_t)bh * KPROJ + kploc + r) * DKH + d] = f2bf(acc[mi][ni][r]);
      } else {
        union { u16 s[4]; uint2 v; } pk;
#pragma unroll
        for (int r = 0; r < 4; ++r) pk.s[r] = f2bf(acc[mi][ni][r]);
        *(uint2*)(VpT + ((size_t)bh * DKH + d) * KPROJ + kploc) = pk.v;
      }
    }
  }
}

// ---------- fused scores+softmax+ctx: grid (T/64, B*H), 4 waves, 16 Q-rows/wave ----------
// NOTE: Ctx may alias Q (block reads exactly the slice it writes; reads precede writes,
// separated by __syncthreads; slices disjoint across blocks)
__global__ void __launch_bounds__(256) attn_fused(const u16* Q, const u16* __restrict__ Kp,
                                                  const u16* __restrict__ VpT, u16* Ctx) {
  __shared__ __align__(16) u16 Ps[64 * KPROJ];
  const int bh = blockIdx.y, b = bh >> 4, h = bh & 15;
  const int t0 = blockIdx.x * 64;
  const int tid = threadIdx.x, wid = tid >> 6, lane = tid & 63;
  const int quad = lane >> 4, l16 = lane & 15;
  const int row0 = wid * 16;
  const u16* Qb = Q + ((size_t)b * T_SEQ + t0 + row0) * DMODEL + h * DKH;
  const u16* Kpb = Kp + (size_t)bh * KPROJ * DKH;
  const u16* Vpb = VpT + (size_t)bh * DKH * KPROJ;

  // scores: 16 rows x 256 cols, K = 64 (2 mfma k-steps)
  f32x4 s[16] = {};
#pragma unroll
  for (int kk = 0; kk < 2; ++kk) {
    short8 a = *(const short8*)(Qb + (size_t)l16 * DMODEL + kk * 32 + quad * 8);
#pragma unroll
    for (int ni = 0; ni < 16; ++ni) {
      short8 bf = *(const short8*)(Kpb + (size_t)(ni * 16 + l16) * DKH + kk * 32 + quad * 8);
      s[ni] = __builtin_amdgcn_mfma_f32_16x16x32_bf16(a, bf, s[ni], 0, 0, 0);
    }
  }

  // softmax over kp (per acc row: row = quad*4+r, cols spread over 16 lanes x 16 tiles)
  const float scale = 0.125f;  // 1/sqrt(64)
#pragma unroll
  for (int r = 0; r < 4; ++r) {
    float mx = -60.0f;
#pragma unroll
    for (int ni = 0; ni < 16; ++ni) {
      // clamp: legit |score| <~ 10; NaN/Inf firewall (IEEE fmin/fmax drop NaN)
      float v = fminf(fmaxf(s[ni][r] * scale, -60.0f), 60.0f);
      s[ni][r] = v; mx = fmaxf(mx, v);
    }
#pragma unroll
    for (int m = 1; m < 16; m <<= 1) mx = fmaxf(mx, __shfl_xor(mx, m));
    float sum = 0.f;
#pragma unroll
    for (int ni = 0; ni < 16; ++ni) {
      float e = __expf(s[ni][r] - mx); s[ni][r] = e; sum += e;
    }
#pragma unroll
    for (int m = 1; m < 16; m <<= 1) sum += __shfl_xor(sum, m);
    const float inv = 1.0f / sum;
#pragma unroll
    for (int ni = 0; ni < 16; ++ni)
      Ps[(row0 + quad * 4 + r) * KPROJ + ni * 16 + l16] = f2bf(s[ni][r] * inv);
  }
  __syncthreads();

  // ctx = P(16x256) @ Vp(256x64): K = 256 (8 k-steps), B^T = VpT
  f32x4 c[4] = {};
#pragma unroll
  for (int kki = 0; kki < 8; ++kki) {
    short8 a = *(const short8*)(Ps + (row0 + l16) * KPROJ + kki * 32 + quad * 8);
#pragma unroll
    for (int ni = 0; ni < 4; ++ni) {
      short8 bf = *(const short8*)(Vpb + (size_t)(ni * 16 + l16) * KPROJ + kki * 32 + quad * 8);
      c[ni] = __builtin_amdgcn_mfma_f32_16x16x32_bf16(a, bf, c[ni], 0, 0, 0);
    }
  }
#pragma unroll
  for (int ni = 0; ni < 4; ++ni)
#pragma unroll
    for (int r = 0; r < 4; ++r)
      Ctx[((size_t)b * T_SEQ + t0 + row0 + quad * 4 + r) * DMODEL + h * DKH + ni * 16 + l16] =
          f2bf(c[ni][r]);
}

extern "C" void kernel_launch(void* const* d_in, const int* in_sizes, int n_in,
                              void* d_out, int out_size, void* d_ws, size_t ws_size,
                              hipStream_t stream) {
  (void)in_sizes; (void)n_in; (void)out_size; (void)ws_size;

  int* flag = (int*)d_ws;
  u16* base = (u16*)d_ws + 16;       // keep 16B alignment for tensors
  const size_t WSZ = 1048576;        // 1024*1024 == 256*4096 == 64*256*64
  const size_t QSZ = 16777216;       // 4*4096*1024
  u16* wqT = base + 0 * WSZ;
  u16* wkT = base + 1 * WSZ;
  u16* wvT = base + 2 * WSZ;
  u16* woT = base + 3 * WSZ;
  u16* ekT = base + 4 * WSZ;
  u16* evT = base + 5 * WSZ;
  u16* Kt  = base + 6 * WSZ;         // (b,h,d,t); later reused for Q then ctx
  u16* Vt  = Kt + QSZ;               // (b,h,d,t)
  u16* Kp  = Vt + QSZ;               // (b,h,kp,d)
  u16* VpT = Kp + WSZ;               // (b,h,d,kp)
  u16* xbf = (u16*)d_out;            // x as bf16, scratch in d_out (dead before final gemm)
  u16* Q   = Kt;                     // Q written after proj_bt consumes Kt

  sniff_dtype<<<1, 64, 0, stream>>>((const u16*)d_in[0], flag);
  convert_x<<<QSZ / 2048, 256, 0, stream>>>(d_in[0], xbf, flag, (int)QSZ);

  dim3 tb(32, 8);
  transpose_cvt<<<dim3(32, 32), tb, 0, stream>>>(d_in[1], wqT, 1024, 1024, flag);
  transpose_cvt<<<dim3(32, 32), tb, 0, stream>>>(d_in[2], wkT, 1024, 1024, flag);
  transpose_cvt<<<dim3(32, 32), tb, 0, stream>>>(d_in[3], wvT, 1024, 1024, flag);
  transpose_cvt<<<dim3(32, 32), tb, 0, stream>>>(d_in[6], woT, 1024, 1024, flag);
  transpose_cvt<<<dim3(8, 128), tb, 0, stream>>>(d_in[4], ekT, 4096, 256, flag);
  transpose_cvt<<<dim3(8, 128), tb, 0, stream>>>(d_in[5], evT, 4096, 256, flag);

  dim3 g1(8, 128);  // (N/128, M/128)
  gemm_bt<2><<<g1, 256, 0, stream>>>(xbf, wkT, nullptr, Kt, flag, 16384, 1024, 1024);
  gemm_bt<2><<<g1, 256, 0, stream>>>(xbf, wvT, nullptr, Vt, flag, 16384, 1024, 1024);

  proj_bt<<<dim3(2, 64, 2), 256, 0, stream>>>(ekT, evT, Kt, Vt, Kp, VpT);

  // Q into Kt's slot (Kt dead after proj_bt)
  gemm_bt<0><<<g1, 256, 0, stream>>>(xbf, wqT, nullptr, Q, flag, 16384, 1024, 1024);

  attn_fused<<<dim3(64, 64), 256, 0, stream>>>(Q, Kp, VpT, Q /*ctx in-place*/);

  // xbf (in d_out) is dead; write final output (bf16 or fp32 per flag)
  gemm_bt<1><<<g1, 256, 0, stream>>>(Q, woT, d_in[7], d_out, flag, 16384, 1024, 1024);
}

// Round 4
// 620.855 us; speedup vs baseline: 1.1245x; 1.1245x over previous
//
#include <hip/hip_runtime.h>

typedef unsigned short u16;
typedef __attribute__((ext_vector_type(8))) short short8;   // 8 bf16 = 4 VGPRs (MFMA A/B frag)
typedef __attribute__((ext_vector_type(4))) float f32x4;    // MFMA C/D frag

#define T_SEQ 4096
#define DMODEL 1024
#define NH 16
#define DKH 64
#define KPROJ 256

// ---------- bf16 helpers (bit-level, RNE) ----------
__device__ __forceinline__ u16 f2bf(float f) {
  union { float f; unsigned u; } v; v.f = f;
  unsigned r = v.u + 0x7FFFu + ((v.u >> 16) & 1u);
  return (u16)(r >> 16);
}
__device__ __forceinline__ float bf2f(u16 h) {
  union { unsigned u; float f; } v; v.u = ((unsigned)h) << 16; return v.f;
}

// ---------- dtype sniffer: fp32 read as u16 pairs -> ~0.4% NaN/Inf bf16 patterns ----------
__global__ void sniff_dtype(const u16* __restrict__ x, int* __restrict__ flag) {
  int c = 0;
  for (int i = threadIdx.x; i < 8192; i += 64)
    if ((x[2 * i] & 0x7F80) == 0x7F80) c++;
#pragma unroll
  for (int m = 1; m < 64; m <<= 1) c += __shfl_xor(c, m);
  if (threadIdx.x == 0) *flag = (c > 0) ? 1 : 0;   // 1 = inputs are float32
}

// ---------- x -> bf16 row-major copy/downconvert ----------
__global__ void convert_x(const void* __restrict__ xin, u16* __restrict__ xout,
                          const int* __restrict__ flag, int n) {
  const int i = (blockIdx.x * 256 + threadIdx.x) * 8;
  if (i >= n) return;
  if (*flag) {
    const float* f = (const float*)xin + i;
    union { u16 s[8]; short8 v; } o;
#pragma unroll
    for (int j = 0; j < 8; ++j) o.s[j] = f2bf(f[j]);
    *(short8*)(xout + i) = o.v;
  } else {
    *(short8*)(xout + i) = *(const short8*)((const u16*)xin + i);
  }
}

// ---------- batched tiled transpose+convert: out[z][c][r] = bf16(in[z][r][c]) ----------
__global__ void transpose_cvt(const void* __restrict__ in, u16* __restrict__ out,
                              int R, int C, const int* __restrict__ flag) {
  __shared__ u16 tile[32][33];
  const bool f32 = (*flag != 0);
  const size_t zoff = (size_t)blockIdx.z * R * C;
  const int c0 = blockIdx.x * 32, r0 = blockIdx.y * 32;
  for (int i = threadIdx.y; i < 32; i += 8) {
    const size_t idx = zoff + (size_t)(r0 + i) * C + c0 + threadIdx.x;
    tile[i][threadIdx.x] = f32 ? f2bf(((const float*)in)[idx]) : ((const u16*)in)[idx];
  }
  __syncthreads();
  for (int i = threadIdx.y; i < 32; i += 8)
    out[zoff + (size_t)(c0 + i) * R + r0 + threadIdx.x] = tile[threadIdx.x][i];
}

// ---------- batched C = A(MxK) @ Bt(NxK)^T, 128x128 tile, BK=32, 4 waves ----------
// MODE 0: C row-major bf16.  MODE 1: + bias[n]; out dtype fp32/bf16 per *flag.
template <int MODE>
__global__ void __launch_bounds__(256) gemm_bt(const u16* __restrict__ A0, const u16* __restrict__ Bt0,
                                               const void* __restrict__ bias, void* __restrict__ Cv,
                                               const int* __restrict__ flag, int M, int N, int K,
                                               size_t sA, size_t sB, size_t sC) {
  __shared__ __align__(16) u16 As[128 * 32];
  __shared__ __align__(16) u16 Bs[128 * 32];
  const u16* A = A0 + blockIdx.z * sA;
  const u16* Bt = Bt0 + blockIdx.z * sB;
  const size_t c0 = blockIdx.z * sC;
  const int tid = threadIdx.x;
  const int wid = tid >> 6, lane = tid & 63;
  const int wm = wid >> 1, wn = wid & 1;
  const int quad = lane >> 4, l16 = lane & 15;
  const int m0 = blockIdx.y * 128, n0 = blockIdx.x * 128;
  const int srow = lane >> 2, scol = (lane & 3) * 8;

  const u16* Ag = A + (size_t)(m0 + srow) * K + scol;
  const u16* Bg = Bt + (size_t)(n0 + srow) * K + scol;

  f32x4 acc[4][4] = {};

  for (int k0 = 0; k0 < K; k0 += 32) {
    short8 va[2], vb[2];
#pragma unroll
    for (int r = 0; r < 2; ++r) {
      const int rowb = r * 64 + wid * 16;
      va[r] = *(const short8*)(Ag + (size_t)rowb * K + k0);
      vb[r] = *(const short8*)(Bg + (size_t)rowb * K + k0);
    }
#pragma unroll
    for (int r = 0; r < 2; ++r) {
      const int row = r * 64 + wid * 16 + srow;
      *(short8*)(As + row * 32 + scol) = va[r];
      *(short8*)(Bs + row * 32 + scol) = vb[r];
    }
    __syncthreads();
    short8 a[4], b[4];
#pragma unroll
    for (int mi = 0; mi < 4; ++mi)
      a[mi] = *(const short8*)(As + (wm * 64 + mi * 16 + l16) * 32 + quad * 8);
#pragma unroll
    for (int ni = 0; ni < 4; ++ni)
      b[ni] = *(const short8*)(Bs + (wn * 64 + ni * 16 + l16) * 32 + quad * 8);
#pragma unroll
    for (int mi = 0; mi < 4; ++mi)
#pragma unroll
      for (int ni = 0; ni < 4; ++ni)
        acc[mi][ni] = __builtin_amdgcn_mfma_f32_16x16x32_bf16(a[mi], b[ni], acc[mi][ni], 0, 0, 0);
    __syncthreads();
  }

  const bool f32out = (MODE == 1) && (*flag != 0);
#pragma unroll
  for (int mi = 0; mi < 4; ++mi) {
#pragma unroll
    for (int ni = 0; ni < 4; ++ni) {
      const int mloc = wm * 64 + mi * 16 + quad * 4;
      const int n = n0 + wn * 64 + ni * 16 + l16;
      float badd = 0.0f;
      if (MODE == 1)
        badd = f32out ? ((const float*)bias)[n] : bf2f(((const u16*)bias)[n]);
#pragma unroll
      for (int r = 0; r < 4; ++r) {
        const size_t oi = c0 + (size_t)(m0 + mloc + r) * N + n;
        if (f32out) ((float*)Cv)[oi] = acc[mi][ni][r] + badd;
        else        ((u16*)Cv)[oi]  = f2bf(acc[mi][ni][r] + badd);
      }
    }
  }
}

// ---------- fused scores+softmax+ctx ----------
// grid (T/64, B*H), 128 threads (2 waves), 32 Q-rows per wave (2 m-tiles of 16).
// Kp[b]: (256 x 1024) row-major, head slice cols h*64..; Vp^T[b]: (1024 x 256), rows h*64+d.
// Ps is wave-private (no barrier). 1/sum folded into ctx epilogue (QK^T and PV share
// the C-layout row mapping row=quad*4+r, so inv stays in the correct lanes).
__global__ void __launch_bounds__(128, 2) attn_fused(const u16* Q, const u16* __restrict__ Kp,
                                                     const u16* __restrict__ VpT, u16* Ctx) {
  __shared__ __align__(16) u16 Ps[2 * 32 * 264];
  const int bh = blockIdx.y, b = bh >> 4, h = bh & 15;
  const int t0 = blockIdx.x * 64;
  const int tid = threadIdx.x, wid = tid >> 6, lane = tid & 63;
  const int quad = lane >> 4, l16 = lane & 15;
  const int row0 = wid * 32;
  const u16* Qb = Q + ((size_t)b * T_SEQ + t0 + row0) * DMODEL + h * DKH;
  const u16* Kpb = Kp + (size_t)b * (KPROJ * DMODEL) + h * DKH;
  const u16* Vpb = VpT + (size_t)b * (DMODEL * KPROJ) + (size_t)(h * DKH) * KPROJ;
  u16* PsW = Ps + wid * (32 * 264);

  // ---- phase 1: scores, 2 m-tiles x 16 n-tiles, K=64 (2 k-steps) ----
  f32x4 s0[16] = {}, s1[16] = {};
#pragma unroll
  for (int kk = 0; kk < 2; ++kk) {
    short8 bfr[16];
#pragma unroll
    for (int ni = 0; ni < 16; ++ni)
      bfr[ni] = *(const short8*)(Kpb + (size_t)(ni * 16 + l16) * DMODEL + kk * 32 + quad * 8);
    short8 a0 = *(const short8*)(Qb + (size_t)l16 * DMODEL + kk * 32 + quad * 8);
    short8 a1 = *(const short8*)(Qb + (size_t)(16 + l16) * DMODEL + kk * 32 + quad * 8);
#pragma unroll
    for (int ni = 0; ni < 16; ++ni) {
      s0[ni] = __builtin_amdgcn_mfma_f32_16x16x32_bf16(a0, bfr[ni], s0[ni], 0, 0, 0);
      s1[ni] = __builtin_amdgcn_mfma_f32_16x16x32_bf16(a1, bfr[ni], s1[ni], 0, 0, 0);
    }
  }

  // ---- softmax (exp2-folded scale; unnormalized e to LDS; keep inv per (mt,r)) ----
  const float sc = 0.125f * 1.44269504f;   // 1/sqrt(64) * log2(e)
  float inv[2][4];
#pragma unroll
  for (int mt = 0; mt < 2; ++mt) {
    f32x4* s = mt ? s1 : s0;
#pragma unroll
    for (int r = 0; r < 4; ++r) {
      float mx = -3.0e38f;
#pragma unroll
      for (int ni = 0; ni < 16; ++ni) {
        float v = fminf(fmaxf(s[ni][r] * sc, -80.0f), 80.0f);   // NaN/Inf firewall
        s[ni][r] = v; mx = fmaxf(mx, v);
      }
#pragma unroll
      for (int m = 1; m < 16; m <<= 1) mx = fmaxf(mx, __shfl_xor(mx, m));
      float sum = 0.f;
      const int prow = mt * 16 + quad * 4 + r;
#pragma unroll
      for (int ni = 0; ni < 16; ++ni) {
        float e = exp2f(s[ni][r] - mx);
        sum += e;
        PsW[prow * 264 + ni * 16 + l16] = f2bf(e);
      }
#pragma unroll
      for (int m = 1; m < 16; m <<= 1) sum += __shfl_xor(sum, m);
      inv[mt][r] = 1.0f / sum;
    }
  }

  // ---- phase 2: ctx = P(32x256) @ Vp(256x64), B^T = VpT rows h*64+d ----
  f32x4 c0[4] = {}, c1[4] = {};
#pragma unroll
  for (int kki = 0; kki < 8; ++kki) {
    short8 bfr[4];
#pragma unroll
    for (int ni = 0; ni < 4; ++ni)
      bfr[ni] = *(const short8*)(Vpb + (size_t)(ni * 16 + l16) * KPROJ + kki * 32 + quad * 8);
    short8 a0 = *(const short8*)(PsW + (l16) * 264 + kki * 32 + quad * 8);
    short8 a1 = *(const short8*)(PsW + (16 + l16) * 264 + kki * 32 + quad * 8);
#pragma unroll
    for (int ni = 0; ni < 4; ++ni) {
      c0[ni] = __builtin_amdgcn_mfma_f32_16x16x32_bf16(a0, bfr[ni], c0[ni], 0, 0, 0);
      c1[ni] = __builtin_amdgcn_mfma_f32_16x16x32_bf16(a1, bfr[ni], c1[ni], 0, 0, 0);
    }
  }
#pragma unroll
  for (int mt = 0; mt < 2; ++mt) {
    f32x4* c = mt ? c1 : c0;
#pragma unroll
    for (int ni = 0; ni < 4; ++ni)
#pragma unroll
      for (int r = 0; r < 4; ++r)
        Ctx[((size_t)b * T_SEQ + t0 + row0 + mt * 16 + quad * 4 + r) * DMODEL + h * DKH +
            ni * 16 + l16] = f2bf(c[ni][r] * inv[mt][r]);
  }
}

extern "C" void kernel_launch(void* const* d_in, const int* in_sizes, int n_in,
                              void* d_out, int out_size, void* d_ws, size_t ws_size,
                              hipStream_t stream) {
  (void)in_sizes; (void)n_in; (void)out_size; (void)ws_size;

  int* flag = (int*)d_ws;
  u16* base = (u16*)d_ws + 16;
  const size_t WSZ = 1048576;        // 1024*1024
  const size_t XSZ = 16777216;       // 4*4096*1024
  u16* wqT   = base + 0 * WSZ;
  u16* wkT   = base + 1 * WSZ;
  u16* wvT   = base + 2 * WSZ;
  u16* woT   = base + 3 * WSZ;
  u16* ekevT = base + 4 * WSZ;       // [ekT(256x4096); evT(256x4096)] = 2M u16
  u16* xT    = base + 6 * WSZ;       // (4, 1024, 4096)
  u16* xE    = xT + XSZ;             // (4, 512, 1024): rows 0-255 = Ek^T x, 256-511 = Ev^T x
  u16* Kp    = xE + 4 * 524288;      // (4, 256, 1024)
  u16* VpT   = Kp + 4 * 262144;      // (4, 1024, 256)
  u16* Q     = VpT + 4 * 262144;     // (4, 4096, 1024); ctx in-place
  u16* xbf   = (u16*)d_out;          // x bf16 scratch in d_out (dead before final gemm)

  sniff_dtype<<<1, 64, 0, stream>>>((const u16*)d_in[0], flag);
  convert_x<<<XSZ / 2048, 256, 0, stream>>>(d_in[0], xbf, flag, (int)XSZ);

  dim3 tb(32, 8);
  transpose_cvt<<<dim3(32, 32, 1), tb, 0, stream>>>(d_in[1], wqT, 1024, 1024, flag);
  transpose_cvt<<<dim3(32, 32, 1), tb, 0, stream>>>(d_in[2], wkT, 1024, 1024, flag);
  transpose_cvt<<<dim3(32, 32, 1), tb, 0, stream>>>(d_in[3], wvT, 1024, 1024, flag);
  transpose_cvt<<<dim3(32, 32, 1), tb, 0, stream>>>(d_in[6], woT, 1024, 1024, flag);
  transpose_cvt<<<dim3(8, 128, 1), tb, 0, stream>>>(d_in[4], ekevT, 4096, 256, flag);
  transpose_cvt<<<dim3(8, 128, 1), tb, 0, stream>>>(d_in[5], ekevT + KPROJ * T_SEQ, 4096, 256, flag);
  transpose_cvt<<<dim3(32, 128, 4), tb, 0, stream>>>(d_in[0], xT, 4096, 1024, flag);

  // xE[b] = [Ek;Ev]^T @ x[b]  -> (512 x 1024), K = 4096
  gemm_bt<0><<<dim3(8, 4, 4), 256, 0, stream>>>(ekevT, xT, nullptr, xE, flag,
                                                512, 1024, 4096, 0, (size_t)DMODEL * T_SEQ, 524288);
  // Kp[b] = xEk[b] @ Wk -> (256 x 1024), K = 1024
  gemm_bt<0><<<dim3(8, 2, 4), 256, 0, stream>>>(xE, wkT, nullptr, Kp, flag,
                                                256, 1024, 1024, 524288, 0, 262144);
  // Vp^T[b] = Wv^T @ xEv[b]^T -> (1024 x 256), K = 1024
  gemm_bt<0><<<dim3(2, 8, 4), 256, 0, stream>>>(wvT, xE + 262144, nullptr, VpT, flag,
                                                1024, 256, 1024, 0, 524288, 262144);
  // Q = x @ Wq -> (16384 x 1024)
  gemm_bt<0><<<dim3(8, 128, 1), 256, 0, stream>>>(xbf, wqT, nullptr, Q, flag,
                                                  16384, 1024, 1024, 0, 0, 0);

  attn_fused<<<dim3(64, 64), 128, 0, stream>>>(Q, Kp, VpT, Q /*ctx in-place*/);

  // out = ctx @ Wo + bo (fp32 or bf16 per flag); xbf in d_out is dead now
  gemm_bt<1><<<dim3(8, 128, 1), 256, 0, stream>>>(Q, woT, d_in[7], d_out, flag,
                                                  16384, 1024, 1024, 0, 0, 0);
}

// Round 5
// 566.579 us; speedup vs baseline: 1.2322x; 1.0958x over previous
//
#include <hip/hip_runtime.h>

typedef unsigned short u16;
typedef __attribute__((ext_vector_type(8))) short short8;   // 8 bf16 = 4 VGPRs (MFMA A/B frag)
typedef __attribute__((ext_vector_type(4))) float f32x4;    // MFMA C/D frag

#define T_SEQ 4096
#define DMODEL 1024
#define NH 16
#define DKH 64
#define KPROJ 256

// ---------- bf16 helpers (bit-level, RNE) ----------
__device__ __forceinline__ u16 f2bf(float f) {
  union { float f; unsigned u; } v; v.f = f;
  unsigned r = v.u + 0x7FFFu + ((v.u >> 16) & 1u);
  return (u16)(r >> 16);
}
__device__ __forceinline__ float bf2f(u16 h) {
  union { unsigned u; float f; } v; v.u = ((unsigned)h) << 16; return v.f;
}

// ---------- async global->LDS, 16B/lane; LDS base wave-uniform, lane i lands at +16*i ----------
__device__ __forceinline__ void gl2lds16(const u16* g, u16* l) {
  __builtin_amdgcn_global_load_lds(
      (const __attribute__((address_space(1))) unsigned int*)g,
      (__attribute__((address_space(3))) unsigned int*)(unsigned int)(unsigned long long)l,
      16, 0, 0);
}

// ---------- dtype sniffer: fp32 read as u16 pairs -> ~0.4% NaN/Inf bf16 patterns ----------
__global__ void sniff_dtype(const u16* __restrict__ x, int* __restrict__ flag) {
  int c = 0;
  for (int i = threadIdx.x; i < 8192; i += 64)
    if ((x[2 * i] & 0x7F80) == 0x7F80) c++;
#pragma unroll
  for (int m = 1; m < 64; m <<= 1) c += __shfl_xor(c, m);
  if (threadIdx.x == 0) *flag = (c > 0) ? 1 : 0;   // 1 = inputs are float32
}

// ---------- x -> bf16 row-major copy/downconvert ----------
__global__ void convert_x(const void* __restrict__ xin, u16* __restrict__ xout,
                          const int* __restrict__ flag, int n) {
  const int i = (blockIdx.x * 256 + threadIdx.x) * 8;
  if (i >= n) return;
  if (*flag) {
    const float* f = (const float*)xin + i;
    union { u16 s[8]; short8 v; } o;
#pragma unroll
    for (int j = 0; j < 8; ++j) o.s[j] = f2bf(f[j]);
    *(short8*)(xout + i) = o.v;
  } else {
    *(short8*)(xout + i) = *(const short8*)((const u16*)xin + i);
  }
}

// ---------- batched tiled transpose+convert: out[z][c][r] = bf16(in[z][r][c]) ----------
__global__ void transpose_cvt(const void* __restrict__ in, u16* __restrict__ out,
                              int R, int C, const int* __restrict__ flag) {
  __shared__ u16 tile[32][33];
  const bool f32 = (*flag != 0);
  const size_t zoff = (size_t)blockIdx.z * R * C;
  const int c0 = blockIdx.x * 32, r0 = blockIdx.y * 32;
  for (int i = threadIdx.y; i < 32; i += 8) {
    const size_t idx = zoff + (size_t)(r0 + i) * C + c0 + threadIdx.x;
    tile[i][threadIdx.x] = f32 ? f2bf(((const float*)in)[idx]) : ((const u16*)in)[idx];
  }
  __syncthreads();
  for (int i = threadIdx.y; i < 32; i += 8)
    out[zoff + (size_t)(c0 + i) * R + r0 + threadIdx.x] = tile[threadIdx.x][i];
}

// ---------- split-K reduce: xE[b][j] = bf16(sum_s P[(b*4+s)*stride + j]) ----------
__global__ void reduce_splitk(const float* __restrict__ P, u16* __restrict__ out) {
  const int b = blockIdx.y;
  const int j = (blockIdx.x * 256 + threadIdx.x) * 8;
  const float* p = P + (size_t)b * 4 * 524288 + j;
  float acc[8] = {};
#pragma unroll
  for (int s = 0; s < 4; ++s) {
    const float4 v0 = *(const float4*)(p + (size_t)s * 524288);
    const float4 v1 = *(const float4*)(p + (size_t)s * 524288 + 4);
    acc[0] += v0.x; acc[1] += v0.y; acc[2] += v0.z; acc[3] += v0.w;
    acc[4] += v1.x; acc[5] += v1.y; acc[6] += v1.z; acc[7] += v1.w;
  }
  union { u16 s[8]; short8 v; } o;
#pragma unroll
  for (int k = 0; k < 8; ++k) o.s[k] = f2bf(acc[k]);
  *(short8*)(out + (size_t)b * 524288 + j) = o.v;
}

// ---------- batched C = A(MxK') @ Bt(NxK')^T, 128x128 tile, BK=32, 4 waves ----------
// Staging via global_load_lds width=16 (m97 pattern).
// MODE 0: bf16 C; batch strides sA/sB/sC, ldA=ldB=K.
// MODE 1: + bias[n]; out dtype fp32/bf16 per *flag.
// MODE 2: split-K fp32 partials: z = b*4+s; kstart = s*K; P block z of M*N floats.
template <int MODE>
__global__ void __launch_bounds__(256) gemm_bt(const u16* __restrict__ A0, const u16* __restrict__ Bt0,
                                               const void* __restrict__ bias, void* __restrict__ Cv,
                                               const int* __restrict__ flag, int M, int N, int K,
                                               int ldA, int ldB, size_t sA, size_t sB, size_t sC) {
  __shared__ __align__(16) u16 As[128 * 32];
  __shared__ __align__(16) u16 Bs[128 * 32];
  const int z = blockIdx.z;
  const int bb = (MODE == 2) ? (z >> 2) : z;
  const int kstart = (MODE == 2) ? ((z & 3) * K) : 0;
  const u16* A = A0 + (size_t)bb * sA;
  const u16* Bt = Bt0 + (size_t)bb * sB;
  const int tid = threadIdx.x;
  const int wid = tid >> 6, lane = tid & 63;
  const int wm = wid >> 1, wn = wid & 1;
  const int quad = lane >> 4, l16 = lane & 15;
  const int m0 = blockIdx.y * 128, n0 = blockIdx.x * 128;
  const int srow = lane >> 2, scol = (lane & 3) * 8;

  const u16* Ag = A + (size_t)(m0 + srow) * ldA + scol + kstart;
  const u16* Bg = Bt + (size_t)(n0 + srow) * ldB + scol + kstart;

  f32x4 acc[4][4] = {};

  for (int k0 = 0; k0 < K; k0 += 32) {
#pragma unroll
    for (int r = 0; r < 2; ++r) {
      const int rowb = r * 64 + wid * 16;               // wave-uniform LDS base
      gl2lds16(Ag + (size_t)rowb * ldA + k0, As + rowb * 32);
      gl2lds16(Bg + (size_t)rowb * ldB + k0, Bs + rowb * 32);
    }
    __syncthreads();
    short8 a[4], b[4];
#pragma unroll
    for (int mi = 0; mi < 4; ++mi)
      a[mi] = *(const short8*)(As + (wm * 64 + mi * 16 + l16) * 32 + quad * 8);
#pragma unroll
    for (int ni = 0; ni < 4; ++ni)
      b[ni] = *(const short8*)(Bs + (wn * 64 + ni * 16 + l16) * 32 + quad * 8);
#pragma unroll
    for (int mi = 0; mi < 4; ++mi)
#pragma unroll
      for (int ni = 0; ni < 4; ++ni)
        acc[mi][ni] = __builtin_amdgcn_mfma_f32_16x16x32_bf16(a[mi], b[ni], acc[mi][ni], 0, 0, 0);
    __syncthreads();
  }

  const bool f32out = (MODE == 1) && (*flag != 0);
  float* Pz = (MODE == 2) ? ((float*)Cv + (size_t)z * M * N) : nullptr;
#pragma unroll
  for (int mi = 0; mi < 4; ++mi) {
#pragma unroll
    for (int ni = 0; ni < 4; ++ni) {
      const int mloc = wm * 64 + mi * 16 + quad * 4;
      const int n = n0 + wn * 64 + ni * 16 + l16;
      float badd = 0.0f;
      if (MODE == 1)
        badd = f32out ? ((const float*)bias)[n] : bf2f(((const u16*)bias)[n]);
#pragma unroll
      for (int r = 0; r < 4; ++r) {
        if (MODE == 2) {
          Pz[(size_t)(m0 + mloc + r) * N + n] = acc[mi][ni][r];
        } else {
          const size_t oi = (size_t)bb * sC + (size_t)(m0 + mloc + r) * N + n;
          if (f32out) ((float*)Cv)[oi] = acc[mi][ni][r] + badd;
          else        ((u16*)Cv)[oi]  = f2bf(acc[mi][ni][r] + badd);
        }
      }
    }
  }
}

// ---------- fused scores+softmax+ctx ----------
// grid (T/64, B*H), 128 threads (2 waves), 32 Q-rows per wave (2 m-tiles of 16).
// Kp[b]: (256 x 1024) row-major, head slice cols h*64..; Vp^T[b]: (1024 x 256), rows h*64+d.
// Ps wave-private (no barrier); 1/sum folded into ctx epilogue (same C-layout row mapping).
__global__ void __launch_bounds__(128, 2) attn_fused(const u16* Q, const u16* __restrict__ Kp,
                                                     const u16* __restrict__ VpT, u16* Ctx) {
  __shared__ __align__(16) u16 Ps[2 * 32 * 264];
  const int bh = blockIdx.y, b = bh >> 4, h = bh & 15;
  const int t0 = blockIdx.x * 64;
  const int tid = threadIdx.x, wid = tid >> 6, lane = tid & 63;
  const int quad = lane >> 4, l16 = lane & 15;
  const int row0 = wid * 32;
  const u16* Qb = Q + ((size_t)b * T_SEQ + t0 + row0) * DMODEL + h * DKH;
  const u16* Kpb = Kp + (size_t)b * (KPROJ * DMODEL) + h * DKH;
  const u16* Vpb = VpT + (size_t)b * (DMODEL * KPROJ) + (size_t)(h * DKH) * KPROJ;
  u16* PsW = Ps + wid * (32 * 264);

  f32x4 s0[16] = {}, s1[16] = {};
#pragma unroll
  for (int kk = 0; kk < 2; ++kk) {
    short8 bfr[16];
#pragma unroll
    for (int ni = 0; ni < 16; ++ni)
      bfr[ni] = *(const short8*)(Kpb + (size_t)(ni * 16 + l16) * DMODEL + kk * 32 + quad * 8);
    short8 a0 = *(const short8*)(Qb + (size_t)l16 * DMODEL + kk * 32 + quad * 8);
    short8 a1 = *(const short8*)(Qb + (size_t)(16 + l16) * DMODEL + kk * 32 + quad * 8);
#pragma unroll
    for (int ni = 0; ni < 16; ++ni) {
      s0[ni] = __builtin_amdgcn_mfma_f32_16x16x32_bf16(a0, bfr[ni], s0[ni], 0, 0, 0);
      s1[ni] = __builtin_amdgcn_mfma_f32_16x16x32_bf16(a1, bfr[ni], s1[ni], 0, 0, 0);
    }
  }

  const float sc = 0.125f * 1.44269504f;   // 1/sqrt(64) * log2(e)
  float inv[2][4];
#pragma unroll
  for (int mt = 0; mt < 2; ++mt) {
    f32x4* s = mt ? s1 : s0;
#pragma unroll
    for (int r = 0; r < 4; ++r) {
      float mx = -3.0e38f;
#pragma unroll
      for (int ni = 0; ni < 16; ++ni) {
        float v = fminf(fmaxf(s[ni][r] * sc, -80.0f), 80.0f);   // NaN/Inf firewall
        s[ni][r] = v; mx = fmaxf(mx, v);
      }
#pragma unroll
      for (int m = 1; m < 16; m <<= 1) mx = fmaxf(mx, __shfl_xor(mx, m));
      float sum = 0.f;
      const int prow = mt * 16 + quad * 4 + r;
#pragma unroll
      for (int ni = 0; ni < 16; ++ni) {
        float e = exp2f(s[ni][r] - mx);
        sum += e;
        PsW[prow * 264 + ni * 16 + l16] = f2bf(e);
      }
#pragma unroll
      for (int m = 1; m < 16; m <<= 1) sum += __shfl_xor(sum, m);
      inv[mt][r] = 1.0f / sum;
    }
  }

  f32x4 c0[4] = {}, c1[4] = {};
#pragma unroll
  for (int kki = 0; kki < 8; ++kki) {
    short8 bfr[4];
#pragma unroll
    for (int ni = 0; ni < 4; ++ni)
      bfr[ni] = *(const short8*)(Vpb + (size_t)(ni * 16 + l16) * KPROJ + kki * 32 + quad * 8);
    short8 a0 = *(const short8*)(PsW + (l16) * 264 + kki * 32 + quad * 8);
    short8 a1 = *(const short8*)(PsW + (16 + l16) * 264 + kki * 32 + quad * 8);
#pragma unroll
    for (int ni = 0; ni < 4; ++ni) {
      c0[ni] = __builtin_amdgcn_mfma_f32_16x16x32_bf16(a0, bfr[ni], c0[ni], 0, 0, 0);
      c1[ni] = __builtin_amdgcn_mfma_f32_16x16x32_bf16(a1, bfr[ni], c1[ni], 0, 0, 0);
    }
  }
#pragma unroll
  for (int mt = 0; mt < 2; ++mt) {
    f32x4* c = mt ? c1 : c0;
#pragma unroll
    for (int ni = 0; ni < 4; ++ni)
#pragma unroll
      for (int r = 0; r < 4; ++r)
        Ctx[((size_t)b * T_SEQ + t0 + row0 + mt * 16 + quad * 4 + r) * DMODEL + h * DKH +
            ni * 16 + l16] = f2bf(c[ni][r] * inv[mt][r]);
  }
}

extern "C" void kernel_launch(void* const* d_in, const int* in_sizes, int n_in,
                              void* d_out, int out_size, void* d_ws, size_t ws_size,
                              hipStream_t stream) {
  (void)in_sizes; (void)n_in; (void)out_size; (void)ws_size;

  int* flag = (int*)d_ws;
  u16* base = (u16*)d_ws + 16;
  const size_t WSZ = 1048576;        // 1024*1024
  const size_t XSZ = 16777216;       // 4*4096*1024
  u16* wqT   = base + 0 * WSZ;
  u16* wkT   = base + 1 * WSZ;
  u16* wvT   = base + 2 * WSZ;
  u16* woT   = base + 3 * WSZ;
  u16* ekevT = base + 4 * WSZ;       // [ekT(256x4096); evT(256x4096)]
  u16* xT    = base + 6 * WSZ;       // (4, 1024, 4096)
  u16* xE    = xT + XSZ;             // (4, 512, 1024): rows 0-255 = Ek^T x, 256-511 = Ev^T x
  u16* Kp    = xE + 4 * 524288;      // (4, 256, 1024)
  u16* VpT   = Kp + 4 * 262144;      // (4, 1024, 256)
  u16* Q     = VpT + 4 * 262144;     // (4, 4096, 1024); also split-K partial buffer (32 MiB), then ctx
  u16* xbf   = (u16*)d_out;          // x bf16 scratch in d_out (dead before final gemm)
  float* xEp = (float*)Q;            // 16 blocks of 512*1024 fp32 partials (exactly Q's 32 MiB)

  sniff_dtype<<<1, 64, 0, stream>>>((const u16*)d_in[0], flag);
  convert_x<<<XSZ / 2048, 256, 0, stream>>>(d_in[0], xbf, flag, (int)XSZ);

  dim3 tb(32, 8);
  transpose_cvt<<<dim3(32, 32, 1), tb, 0, stream>>>(d_in[1], wqT, 1024, 1024, flag);
  transpose_cvt<<<dim3(32, 32, 1), tb, 0, stream>>>(d_in[2], wkT, 1024, 1024, flag);
  transpose_cvt<<<dim3(32, 32, 1), tb, 0, stream>>>(d_in[3], wvT, 1024, 1024, flag);
  transpose_cvt<<<dim3(32, 32, 1), tb, 0, stream>>>(d_in[6], woT, 1024, 1024, flag);
  transpose_cvt<<<dim3(8, 128, 1), tb, 0, stream>>>(d_in[4], ekevT, 4096, 256, flag);
  transpose_cvt<<<dim3(8, 128, 1), tb, 0, stream>>>(d_in[5], ekevT + KPROJ * T_SEQ, 4096, 256, flag);
  transpose_cvt<<<dim3(32, 128, 4), tb, 0, stream>>>(d_in[0], xT, 4096, 1024, flag);

  // xE[b] = [Ek;Ev]^T @ x[b], split-K x4: z = b*4+s, each K-chunk 1024
  gemm_bt<2><<<dim3(8, 4, 16), 256, 0, stream>>>(ekevT, xT, nullptr, xEp, flag,
                                                 512, 1024, 1024, 4096, 4096,
                                                 0, (size_t)DMODEL * T_SEQ, 0);
  reduce_splitk<<<dim3(256, 4), 256, 0, stream>>>(xEp, xE);

  // Kp[b] = xEk[b] @ Wk -> (256 x 1024)
  gemm_bt<0><<<dim3(8, 2, 4), 256, 0, stream>>>(xE, wkT, nullptr, Kp, flag,
                                                256, 1024, 1024, 1024, 1024, 524288, 0, 262144);
  // Vp^T[b] = Wv^T @ xEv[b]^T -> (1024 x 256)
  gemm_bt<0><<<dim3(2, 8, 4), 256, 0, stream>>>(wvT, xE + 262144, nullptr, VpT, flag,
                                                1024, 256, 1024, 1024, 1024, 0, 524288, 262144);
  // Q = x @ Wq -> (16384 x 1024); overwrites the (now dead) split-K partials
  gemm_bt<0><<<dim3(8, 128, 1), 256, 0, stream>>>(xbf, wqT, nullptr, Q, flag,
                                                  16384, 1024, 1024, 1024, 1024, 0, 0, 0);

  attn_fused<<<dim3(64, 64), 128, 0, stream>>>(Q, Kp, VpT, Q /*ctx in-place*/);

  // out = ctx @ Wo + bo (fp32 or bf16 per flag); xbf in d_out is dead now
  gemm_bt<1><<<dim3(8, 128, 1), 256, 0, stream>>>(Q, woT, d_in[7], d_out, flag,
                                                  16384, 1024, 1024, 1024, 1024, 0, 0, 0);
}